// Round 1
// baseline (65.920 us; speedup 1.0000x reference)
//
#include <hip/hip_runtime.h>

#define DIM 32
#define H1 64      // hidden layer
#define XW 96      // 3*DIM input width
#define BLK 256

__global__ __launch_bounds__(BLK) void mtn_fused(
    const int* __restrict__ uid, const int* __restrict__ iid,
    const float* __restrict__ Uw, const float* __restrict__ Qw,
    const float* __restrict__ Aw, const float* __restrict__ Bw,
    const float* __restrict__ W1, const float* __restrict__ b1g,
    const float* __restrict__ W2, const float* __restrict__ b2g,
    float* __restrict__ out, int batch)
{
    __shared__ float W1s[H1 * XW];   // 24 KB, row-major [64][96]
    __shared__ float W2s[H1];
    __shared__ float b1s[H1];

    // cooperative stage of weights into LDS (6144 floats = 1536 float4)
    {
        const float4* src = (const float4*)W1;
        float4* dst = (float4*)W1s;
        for (int t = threadIdx.x; t < H1 * XW / 4; t += BLK)
            dst[t] = src[t];
        if (threadIdx.x < H1) {
            W2s[threadIdx.x] = W2[threadIdx.x];
            b1s[threadIdx.x] = b1g[threadIdx.x];
        }
    }
    __syncthreads();

    int i = blockIdx.x * BLK + threadIdx.x;
    if (i >= batch) return;

    int u_idx = uid[i];
    int q_idx = iid[i];

    const float4* up = (const float4*)(Uw + (long long)u_idx * DIM);
    const float4* qp = (const float4*)(Qw + (long long)q_idx * DIM);

    float u[DIM], q[DIM], uq[DIM];
    float dot = 0.f;
#pragma unroll
    for (int k = 0; k < DIM / 4; ++k) {
        float4 uv = up[k];
        float4 qv = qp[k];
        u[4*k+0] = uv.x; u[4*k+1] = uv.y; u[4*k+2] = uv.z; u[4*k+3] = uv.w;
        q[4*k+0] = qv.x; q[4*k+1] = qv.y; q[4*k+2] = qv.z; q[4*k+3] = qv.w;
        uq[4*k+0] = uv.x * qv.x;
        uq[4*k+1] = uv.y * qv.y;
        uq[4*k+2] = uv.z * qv.z;
        uq[4*k+3] = uv.w * qv.w;
        dot += uq[4*k+0] + uq[4*k+1] + uq[4*k+2] + uq[4*k+3];
    }

    float pred = dot + Aw[u_idx] + Bw[q_idx];
    out[i] = pred;

    // MLP: h = relu(x @ W1^T + b1); score = relu(h . W2 + b2)
    float score = b2g[0];
#pragma unroll 4
    for (int j = 0; j < H1; ++j) {
        const float4* w = (const float4*)(W1s + j * XW);
        float a0 = b1s[j], a1 = 0.f, a2 = 0.f;
#pragma unroll
        for (int k = 0; k < DIM / 4; ++k) {
            float4 w0 = w[k];          // weights for u block
            float4 w1 = w[k + 8];      // weights for q block
            float4 w2v = w[k + 16];    // weights for uq block
            a0 = fmaf(u[4*k+0],  w0.x,  a0);
            a0 = fmaf(u[4*k+1],  w0.y,  a0);
            a0 = fmaf(u[4*k+2],  w0.z,  a0);
            a0 = fmaf(u[4*k+3],  w0.w,  a0);
            a1 = fmaf(q[4*k+0],  w1.x,  a1);
            a1 = fmaf(q[4*k+1],  w1.y,  a1);
            a1 = fmaf(q[4*k+2],  w1.z,  a1);
            a1 = fmaf(q[4*k+3],  w1.w,  a1);
            a2 = fmaf(uq[4*k+0], w2v.x, a2);
            a2 = fmaf(uq[4*k+1], w2v.y, a2);
            a2 = fmaf(uq[4*k+2], w2v.z, a2);
            a2 = fmaf(uq[4*k+3], w2v.w, a2);
        }
        float h = fmaxf(a0 + a1 + a2, 0.f);
        score = fmaf(h, W2s[j], score);
    }
    out[batch + i] = fmaxf(score, 0.f);
}

extern "C" void kernel_launch(void* const* d_in, const int* in_sizes, int n_in,
                              void* d_out, int out_size, void* d_ws, size_t ws_size,
                              hipStream_t stream) {
    const int*   uid = (const int*)  d_in[0];
    const int*   iid = (const int*)  d_in[1];
    const float* Uw  = (const float*)d_in[2];
    const float* Qw  = (const float*)d_in[3];
    const float* Aw  = (const float*)d_in[4];
    const float* Bw  = (const float*)d_in[5];
    const float* W1  = (const float*)d_in[6];
    const float* b1  = (const float*)d_in[7];
    const float* W2  = (const float*)d_in[8];
    const float* b2  = (const float*)d_in[9];
    float* out = (float*)d_out;
    int batch = in_sizes[0];
    int blocks = (batch + BLK - 1) / BLK;
    hipLaunchKernelGGL(mtn_fused, dim3(blocks), dim3(BLK), 0, stream,
                       uid, iid, Uw, Qw, Aw, Bw, W1, b1, W2, b2, out, batch);
}